// Round 18
// baseline (738.897 us; speedup 1.0000x reference)
//
#include <hip/hip_runtime.h>
#include <hip/hip_bf16.h>
#include <cstdint>

#define DIM   2048
#define MROWS 16384  // B*S = 8*2048
#define PLANE (MROWS * (size_t)DIM)

typedef __bf16 bf16x8 __attribute__((ext_vector_type(8)));
typedef float  f32x4  __attribute__((ext_vector_type(4)));
typedef unsigned short u16;
typedef unsigned int   u32;

#define BARRIER() asm volatile("s_barrier" ::: "memory")
#define WAITVM(N) asm volatile("s_waitcnt vmcnt(" #N ")" ::: "memory")

// ---- ws layout ----
// [0,32MB) ternary W f,c,g,o | [32,96MB) x bf16 | [96,160MB) gh bf16

__device__ __forceinline__ u16 ternary_bits(float w) {
    u32 u = __float_as_uint(w);
    u16 s = (u16)((u >> 16) & 0x8000u);
    return (__builtin_fabsf(w) < 0.33f) ? (u16)0 : (u16)(0x3F80u | s);
}

__device__ __forceinline__ u16 f2bf_rne(float f) {
    u32 u = __float_as_uint(f);
    u32 r = (u + 0x7FFFu + ((u >> 16) & 1u)) >> 16;
    return (u16)r;
}

__device__ __forceinline__ void gload16(const void* g, void* l) {
    __builtin_amdgcn_global_load_lds(
        (const __attribute__((address_space(1))) void*)g,
        (__attribute__((address_space(3))) void*)l,
        16, 0, 0);
}

// ---------------- prep kernels ----------------

__global__ void prep_weights(const float* __restrict__ wf, const float* __restrict__ wc,
                             const float* __restrict__ wg, const float* __restrict__ wo,
                             u16* __restrict__ out) {
    const float* srcs[4] = {wf, wc, wg, wo};
    const float* src = srcs[blockIdx.y];
    u16* dst = out + (size_t)blockIdx.y * (DIM * DIM);
    int e = (blockIdx.x * 256 + threadIdx.x) * 8;
    float4 v0 = *(const float4*)(src + e);
    float4 v1 = *(const float4*)(src + e + 4);
    ushort4 o0, o1;
    o0.x = ternary_bits(v0.x); o0.y = ternary_bits(v0.y);
    o0.z = ternary_bits(v0.z); o0.w = ternary_bits(v0.w);
    o1.x = ternary_bits(v1.x); o1.y = ternary_bits(v1.y);
    o1.z = ternary_bits(v1.z); o1.w = ternary_bits(v1.w);
    *(ushort4*)(dst + e)     = o0;
    *(ushort4*)(dst + e + 4) = o1;
}

__global__ void cast_x(const float* __restrict__ x, u16* __restrict__ xb) {
    size_t e = ((size_t)blockIdx.x * 256 + threadIdx.x) * 8;
    float4 v0 = *(const float4*)(x + e);
    float4 v1 = *(const float4*)(x + e + 4);
    ushort4 o0, o1;
    o0.x = f2bf_rne(v0.x); o0.y = f2bf_rne(v0.y);
    o0.z = f2bf_rne(v0.z); o0.w = f2bf_rne(v0.w);
    o1.x = f2bf_rne(v1.x); o1.y = f2bf_rne(v1.y);
    o1.z = f2bf_rne(v1.z); o1.w = f2bf_rne(v1.w);
    *(ushort4*)(xb + e)     = o0;
    *(ushort4*)(xb + e + 4) = o1;
}

// ---------------- gemm1f: fused-epilogue 8-phase-style GEMM ----------------
// Block tile 256 rows x 128 cols x 3 gates. 512 thr = 8 waves (2m x 4n):
// per-wave 128x32 per gate (M_rep=8, N_rep=2), acc[3][8][2] (192 f32, AGPRs).
// K = 2048 = 64 halves of k32. LDS: 3-slot ring x 40KB (A [256][32] 16KB +
// B 3x[128][32] 24KB) = 120KB. Per half: 3 gate-phases of 16 MFMA:
//   Pg0: rdA(8)+rdB(g0,2); issue stA(h+2)x2;            BAR; MFMA16; BAR
//   Pg1: rdB(g1,2);        issue stB(h+2,g0),(g1);      BAR; MFMA16; BAR
//   Pg2: rdB(g2,2);        issue stB(h+2,g2); WAITVM(5);BAR; MFMA16; BAR
// FIFO audit: 5 issues/half; at Pg2(h) outstanding = h's 5 issues ->
// WAITVM(5) retires through Pg2(h-1) = slot h+1 fully staged, consumed at
// Pg0(h+1). Slot (h+2)%3 written during h = h-1's slot, whose reads finished
// before Pg2(h-1)'s end barrier -> safe. Tails: h=62 WAITVM(0), h=63 resident.
// Epilogue: sigmoid/silu/h/gh computed in-register, written direct.

__global__ __launch_bounds__(512) void gemm1f(
    const u16* __restrict__ xb,      // [16384][2048] bf16
    const u16* __restrict__ wt,      // [6144][2048] bf16 ternary (f,c,g)
    const float* __restrict__ bfv_, const float* __restrict__ bcv_, const float* __restrict__ bgv_,
    const float* __restrict__ hprev, // f32
    float* __restrict__ hout,        // f32 (second half of d_out)
    u16* __restrict__ gh)            // bf16 ws
{
    __shared__ __align__(16) u16 lds[61440];   // 120 KB = 3 slots x 20480 u16

    const int tid  = threadIdx.x;
    const int lane = tid & 63;
    const int wave = tid >> 6;
    const int wm   = wave >> 2;   // 0..1 -> 128-row half
    const int wn   = wave & 3;    // 0..3 -> 32-col quarter (per gate)

    // grid 1024 = 8 XCD x (2 n-fastest x 64 m): A-tile shared by 2 consecutive
    // blocks (L2-hit); W per chunk = 2n x 3 gates x 0.5MB = 3MB < 4MB L2.
    const int xcd   = blockIdx.x & 7;
    const int inner = blockIdx.x >> 3;
    const int ntile = xcd * 2 + (inner & 1);
    const int mtile = inner >> 1;
    const int brow  = mtile * 256;
    const int bcol  = ntile * 128;

    const int gc4  = (tid & 3) ^ ((tid >> 3) & 3);  // swizzled source chunk
    const int fr   = lane & 15;
    const int hi   = lane >> 4;
    const int csw  = (hi ^ ((fr >> 1) & 3)) * 8;    // swizzled read chunk (u16)

    f32x4 acc[3][8][2] = {};   // [gate][mi][ni] — all indices compile-time

    auto stA = [&](int so, int h, int call) {
        const int row = call * 128 + (tid >> 2);
        gload16(xb + (size_t)(brow + row) * DIM + h * 32 + gc4 * 8,
                (u16*)&lds[so + call * 4096 + tid * 8]);
    };
    auto stB = [&](int so, int h, int g) {
        const int row = tid >> 2;
        gload16(wt + (size_t)(g * 2048 + bcol + row) * DIM + h * 32 + gc4 * 8,
                (u16*)&lds[so + 8192 + g * 4096 + tid * 8]);
    };

    auto rdA = [&](int so, bf16x8 (&a)[8]) {
        #pragma unroll
        for (int mi = 0; mi < 8; ++mi)
            a[mi] = *(const bf16x8*)(&lds[so + (wm * 128 + mi * 16 + fr) * 32 + csw]);
    };
    auto rdB = [&](int so, int g, bf16x8 (&bb)[2]) {
        #pragma unroll
        for (int ni = 0; ni < 2; ++ni)
            bb[ni] = *(const bf16x8*)(&lds[so + 8192 + g * 4096 + (wn * 32 + ni * 16 + fr) * 32 + csw]);
    };

    bf16x8 a[8], bb[2];

#define MFG(G)                                                                 \
    __builtin_amdgcn_s_setprio(1);                                             \
    _Pragma("unroll")                                                          \
    for (int ni = 0; ni < 2; ++ni)                                             \
        _Pragma("unroll")                                                      \
        for (int mi = 0; mi < 8; ++mi)                                         \
            acc[G][mi][ni] = __builtin_amdgcn_mfma_f32_16x16x32_bf16(          \
                a[mi], bb[ni], acc[G][mi][ni], 0, 0, 0);                       \
    __builtin_amdgcn_s_setprio(0);

    int s0 = 0, s1 = 20480, s2 = 40960;

    // prologue: stage halves 0,1 (5 calls each); retire half 0
    stA(s0, 0, 0); stA(s0, 0, 1); stB(s0, 0, 0); stB(s0, 0, 1); stB(s0, 0, 2);
    stA(s1, 1, 0); stA(s1, 1, 1); stB(s1, 1, 0); stB(s1, 1, 1); stB(s1, 1, 2);
    WAITVM(5);
    BARRIER();

    #pragma unroll 1
    for (int h = 0; h < 62; ++h) {
        // Pg0
        rdA(s0, a); rdB(s0, 0, bb);
        stA(s2, h + 2, 0); stA(s2, h + 2, 1);
        BARRIER(); MFG(0); BARRIER();
        // Pg1
        rdB(s0, 1, bb);
        stB(s2, h + 2, 0); stB(s2, h + 2, 1);
        BARRIER(); MFG(1); BARRIER();
        // Pg2
        rdB(s0, 2, bb);
        stB(s2, h + 2, 2);
        WAITVM(5);      // retire through Pg2(h-1): slot h+1 fully staged
        BARRIER(); MFG(2); BARRIER();
        int t = s0; s0 = s1; s1 = s2; s2 = t;
    }
    { // h = 62: no staging; drain remaining (h63's 5 loads)
        rdA(s0, a); rdB(s0, 0, bb);
        BARRIER(); MFG(0); BARRIER();
        rdB(s0, 1, bb);
        BARRIER(); MFG(1); BARRIER();
        rdB(s0, 2, bb);
        WAITVM(0);
        BARRIER(); MFG(2); BARRIER();
        int t = s0; s0 = s1; s1 = s2; s2 = t;
    }
    { // h = 63: all resident
        rdA(s0, a); rdB(s0, 0, bb);
        MFG(0);
        rdB(s0, 1, bb);
        MFG(1);
        rdB(s0, 2, bb);
        MFG(2);
    }
#undef MFG

    // fused epilogue: f=sigmoid, c=silu, g=sigmoid, h=f*hp+(1-f)*c, gh=g*h
    #pragma unroll
    for (int ni = 0; ni < 2; ++ni) {
        const int col = bcol + wn * 32 + ni * 16 + fr;
        const float bfv = bfv_[col], bcv = bcv_[col], bgv = bgv_[col];
        #pragma unroll
        for (int mi = 0; mi < 8; ++mi) {
            #pragma unroll
            for (int j = 0; j < 4; ++j) {
                const int row = brow + wm * 128 + mi * 16 + hi * 4 + j;
                const size_t idx = (size_t)row * DIM + col;
                float pf = acc[0][mi][ni][j] + bfv;
                float pc = acc[1][mi][ni][j] + bcv;
                float pg = acc[2][mi][ni][j] + bgv;
                float f  = 1.f / (1.f + __expf(-pf));
                float cc = pc / (1.f + __expf(-pc));
                float g  = 1.f / (1.f + __expf(-pg));
                float hh = f * hprev[idx] + (1.f - f) * cc;
                hout[idx] = hh;
                gh[idx] = f2bf_rne(g * hh);
            }
        }
    }
}

// ---------------- gemm2: o = gh @ Wo^T + bo (R17's 8-phase, unchanged) ----------------

__global__ __launch_bounds__(512) void gemm2o(
    const u16* __restrict__ Amat,   // gh [16384][2048] bf16
    const u16* __restrict__ Wmat,   // Wo ternary bf16
    const float* __restrict__ bias, float* __restrict__ oout)
{
    __shared__ __align__(16) u16 lds[65536];   // 128 KB

    const int tid  = threadIdx.x;
    const int lane = tid & 63;
    const int wave = tid >> 6;
    const int wm   = wave >> 2;
    const int wn   = wave & 3;

    const int xcd   = blockIdx.x & 7;
    const int inner = blockIdx.x >> 3;
    const int brow  = inner * 256;
    const int bcol  = xcd * 256;

    const int gc4  = (tid & 3) ^ ((tid >> 3) & 3);
    const int fr   = lane & 15;
    const int hi   = lane >> 4;
    const int csw  = (hi ^ ((fr >> 1) & 3)) * 8;

    f32x4 acc[8][4] = {};

    const u16* aSrc = Amat + (size_t)(brow + (tid >> 2)) * DIM;
    const u16* bSrc = Wmat + (size_t)(bcol + (tid >> 2)) * DIM;

    auto stA = [&](int b, int h, int t) {
        const int k0 = t * 64 + h * 32;
        u16* dst = &lds[b * 32768 + h * 16384 + tid * 8];
        gload16(aSrc + k0 + gc4 * 8, dst);
        gload16(aSrc + (size_t)128 * DIM + k0 + gc4 * 8, dst + 4096);
    };
    auto stB = [&](int b, int h, int t) {
        const int k0 = t * 64 + h * 32;
        u16* dst = &lds[b * 32768 + h * 16384 + 8192 + tid * 8];
        gload16(bSrc + k0 + gc4 * 8, dst);
        gload16(bSrc + (size_t)128 * DIM + k0 + gc4 * 8, dst + 4096);
    };

    auto rdA = [&](int b, int h, bf16x8 (&a)[8]) {
        const u16* p = &lds[b * 32768 + h * 16384];
        #pragma unroll
        for (int mi = 0; mi < 8; ++mi)
            a[mi] = *(const bf16x8*)(p + (wm * 128 + mi * 16 + fr) * 32 + csw);
    };
    auto rdB = [&](int b, int h, int nh, bf16x8 (&bb)[2]) {
        const u16* p = &lds[b * 32768 + h * 16384 + 8192];
        #pragma unroll
        for (int j = 0; j < 2; ++j)
            bb[j] = *(const bf16x8*)(p + (wn * 64 + (nh * 2 + j) * 16 + fr) * 32 + csw);
    };
    auto mf = [&](bf16x8 (&a)[8], bf16x8 (&bb)[2], int nh) {
        __builtin_amdgcn_s_setprio(1);
        #pragma unroll
        for (int j = 0; j < 2; ++j)
            #pragma unroll
            for (int mi = 0; mi < 8; ++mi)
                acc[mi][nh * 2 + j] =
                    __builtin_amdgcn_mfma_f32_16x16x32_bf16(a[mi], bb[j], acc[mi][nh * 2 + j], 0, 0, 0);
        __builtin_amdgcn_s_setprio(0);
    };

    bf16x8 a[8], bb[2];

    stA(0, 0, 0); stB(0, 0, 0);
    stA(0, 1, 0); stB(0, 1, 0);
    stA(1, 0, 1); stB(1, 0, 1);
    WAITVM(8);
    BARRIER();

    #pragma unroll 1
    for (int t = 0; t < 30; ++t) {
        const int b = t & 1, bn = b ^ 1;
        rdA(b, 0, a); rdB(b, 0, 0, bb);
        stA(bn, 1, t + 1);
        BARRIER(); mf(a, bb, 0); BARRIER();
        rdB(b, 0, 1, bb);
        stB(bn, 1, t + 1);
        WAITVM(8);
        BARRIER(); mf(a, bb, 1); BARRIER();
        rdA(b, 1, a); rdB(b, 1, 0, bb);
        stA(b, 0, t + 2);
        BARRIER(); mf(a, bb, 0); BARRIER();
        rdB(b, 1, 1, bb);
        stB(b, 0, t + 2);
        WAITVM(8);
        BARRIER(); mf(a, bb, 1); BARRIER();
    }
    {
        rdA(0, 0, a); rdB(0, 0, 0, bb);
        stA(1, 1, 31);
        BARRIER(); mf(a, bb, 0); BARRIER();
        rdB(0, 0, 1, bb);
        stB(1, 1, 31);
        WAITVM(8);
        BARRIER(); mf(a, bb, 1); BARRIER();
        rdA(0, 1, a); rdB(0, 1, 0, bb);
        BARRIER(); mf(a, bb, 0); BARRIER();
        rdB(0, 1, 1, bb);
        WAITVM(4);
        BARRIER(); mf(a, bb, 1); BARRIER();
    }
    {
        rdA(1, 0, a); rdB(1, 0, 0, bb);
        BARRIER(); mf(a, bb, 0); BARRIER();
        rdB(1, 0, 1, bb);
        WAITVM(0);
        BARRIER(); mf(a, bb, 1); BARRIER();
        rdA(1, 1, a); rdB(1, 1, 0, bb);
        BARRIER(); mf(a, bb, 0); BARRIER();
        rdB(1, 1, 1, bb);
        mf(a, bb, 1);
    }

    #pragma unroll
    for (int ni = 0; ni < 4; ++ni) {
        const int col = bcol + wn * 64 + ni * 16 + fr;
        const float bv = bias[col];
        #pragma unroll
        for (int mi = 0; mi < 8; ++mi)
            #pragma unroll
            for (int j = 0; j < 4; ++j)
                oout[(size_t)(brow + wm * 128 + mi * 16 + hi * 4 + j) * DIM + col] =
                    acc[mi][ni][j] + bv;
    }
}

extern "C" void kernel_launch(void* const* d_in, const int* in_sizes, int n_in,
                              void* d_out, int out_size, void* d_ws, size_t ws_size,
                              hipStream_t stream) {
    const float* x  = (const float*)d_in[0];
    const float* hp = (const float*)d_in[1];
    const float* wf = (const float*)d_in[2];
    const float* bf = (const float*)d_in[3];
    const float* wc = (const float*)d_in[4];
    const float* bc = (const float*)d_in[5];
    const float* wg = (const float*)d_in[6];
    const float* bg = (const float*)d_in[7];
    const float* wo = (const float*)d_in[8];
    const float* bo = (const float*)d_in[9];

    float* o_out = (float*)d_out;
    float* h_out = o_out + PLANE;

    u16* w_t  = (u16*)d_ws;                              // wf,wc,wg then wo (32MB)
    u16* x_bf = (u16*)((char*)d_ws + 33554432);          // 64MB
    u16* gh   = (u16*)((char*)d_ws + 100663296);         // 64MB

    prep_weights<<<dim3(2048, 4), 256, 0, stream>>>(wf, wc, wg, wo, w_t);
    cast_x<<<dim3(16384), 256, 0, stream>>>(x, x_bf);
    gemm1f<<<dim3(1024), 512, 0, stream>>>(x_bf, w_t, bf, bc, bg, hp, h_out, gh);
    gemm2o<<<dim3(512), 512, 0, stream>>>(gh, w_t + 3 * (size_t)DIM * DIM, bo, o_out);
}